// Round 7
// baseline (562.264 us; speedup 1.0000x reference)
//
#include <hip/hip_runtime.h>
#include <hip/hip_bf16.h>

#define B_  32
#define S_  512
#define D_  768
#define H_  12
#define HD_ 64
#define QKV_ELEMS (B_ * H_ * S_ * HD_)  // 12582912 per tensor

typedef __hip_bfloat16 bf16;
typedef short bf16x8_t __attribute__((ext_vector_type(8)));
typedef float f32x4_t  __attribute__((ext_vector_type(4)));

__device__ __forceinline__ float bf2f(bf16 x) { return __bfloat162float(x); }
__device__ __forceinline__ bf16  f2bf(float x) { return __float2bfloat16(x); }

__device__ __forceinline__ void gl_lds16(const short* g, short* l) {
    __builtin_amdgcn_global_load_lds(
        (const __attribute__((address_space(1))) void*)g,
        (__attribute__((address_space(3))) void*)l, 16, 0, 0);
}

// ---------------------------------------------------------------------------
// fused fp32 -> bf16 conversion for all three arrays (1 launch)
// ---------------------------------------------------------------------------
__global__ __launch_bounds__(256) void f2bf3_kernel(
    const float* __restrict__ a, unsigned short* __restrict__ oa, int na4,
    const float* __restrict__ b, unsigned short* __restrict__ ob, int nb4,
    const float* __restrict__ c, unsigned short* __restrict__ oc, int nc4)
{
    int i = blockIdx.x * 256 + threadIdx.x;
    const float* src; unsigned short* dst; int idx;
    if (i < na4)            { src = a; dst = oa; idx = i; }
    else if (i < na4 + nb4) { src = b; dst = ob; idx = i - na4; }
    else if (i < na4 + nb4 + nc4) { src = c; dst = oc; idx = i - na4 - nb4; }
    else return;
    float4 v = reinterpret_cast<const float4*>(src)[idx];
    ushort4 o;
    o.x = __bfloat16_as_ushort(f2bf(v.x));
    o.y = __bfloat16_as_ushort(f2bf(v.y));
    o.z = __bfloat16_as_ushort(f2bf(v.z));
    o.w = __bfloat16_as_ushort(f2bf(v.w));
    reinterpret_cast<ushort4*>(dst)[idx] = o;
}

// ---------------------------------------------------------------------------
// MFMA GEMM core: BK=32, XOR chunk swizzle, double buffer, 5 blocks/CU.
// Buffers: 128 rows x 32 shorts (64 B/row, 4 chunks of 16 B) = 8 KB each;
// As/Bs = 2 bufs = 16 KB each -> 32 KB/block -> 5 blocks/CU residency.
// Swizzle: global chunk c of row R stored at slot c ^ (R & 3).  Staging is
// 16 x 64 B full-line segments/instr (same L2 line count as 8 x 128 B).
// Fragment ds_read_b128: 8 lanes per 4-bank group x 8 phases = conflict-free.
// Rationale (r6 post-mortem): per-block barrier drains are hidden by cross-
// block wave rotation at 5 blocks/CU, not by deeper per-block pipelining.
// ---------------------------------------------------------------------------
#define GEMM_CORE(As, Bs, Aptr, Bptr, m0, n0, K)                               \
    const int t = threadIdx.x;                                                 \
    const int w = t >> 6, lane = t & 63;                                       \
    const int wr = w >> 1, wc = w & 1;                                         \
    const int quad = lane >> 4, l16 = lane & 15;                               \
    f32x4_t acc[4][4] = {};                                                    \
    const int lrow2 = lane >> 2;                                               \
    const int scol2 = (((lane & 3) ^ (lrow2 & 3)) * 8);                        \
    const int rsw = ((quad ^ (l16 & 3)) * 8);                                  \
    _Pragma("unroll")                                                          \
    for (int j = 0; j < 2; ++j) {                                              \
        int R = j * 64 + w * 16;                                               \
        gl_lds16((Aptr) + (size_t)((m0) + R + lrow2) * (K) + scol2, &(As)[R * 32]); \
        gl_lds16((Bptr) + (size_t)((n0) + R + lrow2) * (K) + scol2, &(Bs)[R * 32]); \
    }                                                                          \
    for (int k0 = 0; k0 < (K); k0 += 32) {                                     \
        const int curo = ((k0 >> 5) & 1) * 4096;                               \
        __syncthreads();                                                       \
        if (k0 + 32 < (K)) {                                                   \
            const int nxo = curo ^ 4096;                                       \
            _Pragma("unroll")                                                  \
            for (int j = 0; j < 2; ++j) {                                      \
                int R = j * 64 + w * 16;                                       \
                gl_lds16((Aptr) + (size_t)((m0) + R + lrow2) * (K) + k0 + 32 + scol2, \
                         &(As)[nxo + R * 32]);                                 \
                gl_lds16((Bptr) + (size_t)((n0) + R + lrow2) * (K) + k0 + 32 + scol2, \
                         &(Bs)[nxo + R * 32]);                                 \
            }                                                                  \
        }                                                                      \
        bf16x8_t af[4], bf_[4];                                                \
        _Pragma("unroll")                                                      \
        for (int tm = 0; tm < 4; ++tm)                                         \
            af[tm] = *(const bf16x8_t*)&(As)[curo + (wr * 64 + tm * 16 + l16) * 32 + rsw]; \
        _Pragma("unroll")                                                      \
        for (int tn = 0; tn < 4; ++tn)                                         \
            bf_[tn] = *(const bf16x8_t*)&(Bs)[curo + (wc * 64 + tn * 16 + l16) * 32 + rsw]; \
        _Pragma("unroll")                                                      \
        for (int tm = 0; tm < 4; ++tm)                                         \
            _Pragma("unroll")                                                  \
            for (int tn = 0; tn < 4; ++tn)                                     \
                acc[tm][tn] = __builtin_amdgcn_mfma_f32_16x16x32_bf16(         \
                    af[tm], bf_[tn], acc[tm][tn], 0, 0, 0);                    \
    }

// ---------------------------------------------------------------------------
// Kernel 1: QKV projection -> q/k/v in [B,H,S,HD] bf16
// ---------------------------------------------------------------------------
__global__ __launch_bounds__(256, 5) void qkv_gemm_mfma(
    const short* __restrict__ A, const short* __restrict__ W,
    const float* __restrict__ bias,
    bf16* __restrict__ Q, bf16* __restrict__ Kp, bf16* __restrict__ Vp)
{
    __shared__ short As[2 * 128 * 32];   // 16 KB
    __shared__ short Bs[2 * 128 * 32];   // 16 KB
    const int n0 = blockIdx.x * 128;
    const int m0 = blockIdx.y * 128;
    GEMM_CORE(As, Bs, A, W, m0, n0, 768)

    const int which = n0 / 768;
    const int h = ((n0 + wc * 64) % 768) >> 6;
    bf16* dst = (which == 0) ? Q : (which == 1) ? Kp : Vp;
    float bv[4];
#pragma unroll
    for (int tn = 0; tn < 4; ++tn) bv[tn] = bias[n0 + wc * 64 + tn * 16 + l16];
#pragma unroll
    for (int tm = 0; tm < 4; ++tm) {
#pragma unroll
        for (int r = 0; r < 4; ++r) {
            int m = m0 + wr * 64 + tm * 16 + quad * 4 + r;
            int b = m >> 9, s = m & 511;
            size_t rb = (((size_t)b * H_ + h) * S_ + s) * HD_;
#pragma unroll
            for (int tn = 0; tn < 4; ++tn)
                dst[rb + tn * 16 + l16] = f2bf(acc[tm][tn][r] + bv[tn]);
        }
    }
}

// ---------------------------------------------------------------------------
// Kernel 3: output projection, fp32 out
// ---------------------------------------------------------------------------
__global__ __launch_bounds__(256, 5) void proj_gemm_mfma(
    const short* __restrict__ A, const short* __restrict__ W,
    const float* __restrict__ bias, float* __restrict__ out)
{
    __shared__ short As[2 * 128 * 32];
    __shared__ short Bs[2 * 128 * 32];
    const int n0 = blockIdx.x * 128;
    const int m0 = blockIdx.y * 128;
    GEMM_CORE(As, Bs, A, W, m0, n0, 768)

    float bv[4];
#pragma unroll
    for (int tn = 0; tn < 4; ++tn) bv[tn] = bias[n0 + wc * 64 + tn * 16 + l16];
#pragma unroll
    for (int tm = 0; tm < 4; ++tm) {
#pragma unroll
        for (int r = 0; r < 4; ++r) {
            int m = m0 + wr * 64 + tm * 16 + quad * 4 + r;
#pragma unroll
            for (int tn = 0; tn < 4; ++tn)
                out[(size_t)m * 768 + n0 + wc * 64 + tn * 16 + l16] =
                    acc[tm][tn][r] + bv[tn];
        }
    }
}

// ---------------------------------------------------------------------------
// Kernel 2: MFMA flash attention (round-6 verified: swizzled Q/K staging,
// wave-private Ps with no barrier before PV).
// ---------------------------------------------------------------------------
#define QT 128
#define KT 64
#define PS 68
#define VS 68

__global__ __launch_bounds__(256, 3) void attn_mfma(
    const short* __restrict__ Qg, const short* __restrict__ Kg,
    const short* __restrict__ Vg, bf16* __restrict__ O)
{
    __shared__ short Qs[QT * 64];     // 16 KB
    __shared__ short Ks[KT * 64];     // 8 KB
    __shared__ short Vt[64 * VS];     // 8.5 KB  [dim][key]
    __shared__ short Ps[QT * PS];     // 17 KB

    const int t = threadIdx.x;
    const int w = t >> 6, lane = t & 63;
    const int quad = lane >> 4, l16 = lane & 15;
    const int lrow = lane >> 3;
    const int scol = (((lane & 7) ^ (lrow & 7)) * 8);
    const int qt = blockIdx.x & 3;
    const int bh = blockIdx.x >> 2;
    const int q0 = qt * QT;
    const size_t base = (size_t)bh * (S_ * HD_);

    // stage Q tile [128 x 64] once (swizzled)
#pragma unroll
    for (int j = 0; j < 4; ++j) {
        int R = j * 32 + w * 8;
        gl_lds16(Qg + base + (size_t)(q0 + R + lrow) * 64 + scol, &Qs[R * 64]);
    }

    const int wq = w * 32;
    f32x4_t Oacc[2][4] = {};
    float lsum[2][4] = {};

    for (int kt = 0; kt < S_; kt += KT) {
        __syncthreads();
        // stage K tile [64 x 64] (swizzled)
#pragma unroll
        for (int j = 0; j < 2; ++j) {
            int R = j * 32 + w * 8;
            gl_lds16(Kg + base + (size_t)(kt + R + lrow) * 64 + scol, &Ks[R * 64]);
        }
        // stage V transposed: Vt[dim][key]
        {
            int k = lane, dg = w;
            const bf16x8_t* gv = (const bf16x8_t*)(Vg + base + (size_t)(kt + k) * 64 + dg * 16);
            bf16x8_t v0 = gv[0], v1 = gv[1];
#pragma unroll
            for (int i = 0; i < 8; ++i) {
                Vt[(dg * 16 + i) * VS + k]     = v0[i];
                Vt[(dg * 16 + 8 + i) * VS + k] = v1[i];
            }
        }
        __syncthreads();

        // QK^T: per-wave S tile [32 queries x 64 keys]
        f32x4_t sc[2][4] = {};
#pragma unroll
        for (int ks = 0; ks < 64; ks += 32) {
            bf16x8_t aq[2], bk[4];
#pragma unroll
            for (int tm = 0; tm < 2; ++tm)
                aq[tm] = *(const bf16x8_t*)&Qs[(wq + tm * 16 + l16) * 64
                        + ((((ks >> 3) + quad) ^ (l16 & 7)) * 8)];
#pragma unroll
            for (int tn = 0; tn < 4; ++tn)
                bk[tn] = *(const bf16x8_t*)&Ks[(tn * 16 + l16) * 64
                        + ((((ks >> 3) + quad) ^ (l16 & 7)) * 8)];
#pragma unroll
            for (int tm = 0; tm < 2; ++tm)
#pragma unroll
                for (int tn = 0; tn < 4; ++tn)
                    sc[tm][tn] = __builtin_amdgcn_mfma_f32_16x16x32_bf16(
                        aq[tm], bk[tn], sc[tm][tn], 0, 0, 0);
        }

        // p = exp(s * 0.125); per-lane row partials; P -> LDS bf16
#pragma unroll
        for (int tm = 0; tm < 2; ++tm) {
#pragma unroll
            for (int r = 0; r < 4; ++r) {
                int row = wq + tm * 16 + quad * 4 + r;
                float rs = 0.f;
#pragma unroll
                for (int tn = 0; tn < 4; ++tn) {
                    float p = __expf(sc[tm][tn][r] * 0.125f);
                    rs += p;
                    Ps[row * PS + tn * 16 + l16] = (short)__bfloat16_as_ushort(f2bf(p));
                }
                lsum[tm][r] += rs;
            }
        }
        // no barrier: Ps rows [wq, wq+32) are wave-private

        // PV: O[32 x 64] per wave
#pragma unroll
        for (int ks = 0; ks < 64; ks += 32) {
            bf16x8_t ap[2], bv[4];
#pragma unroll
            for (int tm = 0; tm < 2; ++tm)
                ap[tm] = *(const bf16x8_t*)&Ps[(wq + tm * 16 + l16) * PS + ks + quad * 8];
#pragma unroll
            for (int tn = 0; tn < 4; ++tn)
                bv[tn] = *(const bf16x8_t*)&Vt[(tn * 16 + l16) * VS + ks + quad * 8];
#pragma unroll
            for (int tm = 0; tm < 2; ++tm)
#pragma unroll
                for (int tn = 0; tn < 4; ++tn)
                    Oacc[tm][tn] = __builtin_amdgcn_mfma_f32_16x16x32_bf16(
                        ap[tm], bv[tn], Oacc[tm][tn], 0, 0, 0);
        }
    }

    // reduce row sums across 16 col-lanes, normalize, store
    float linv[2][4];
#pragma unroll
    for (int tm = 0; tm < 2; ++tm)
#pragma unroll
        for (int r = 0; r < 4; ++r) {
            float v = lsum[tm][r];
            v += __shfl_xor(v, 1, 64);
            v += __shfl_xor(v, 2, 64);
            v += __shfl_xor(v, 4, 64);
            v += __shfl_xor(v, 8, 64);
            linv[tm][r] = 1.f / v;
        }
    const int b = bh / H_, h = bh % H_;
#pragma unroll
    for (int tm = 0; tm < 2; ++tm) {
#pragma unroll
        for (int r = 0; r < 4; ++r) {
            int row = q0 + wq + tm * 16 + quad * 4 + r;
            size_t ob = ((size_t)b * S_ + row) * D_ + h * HD_;
#pragma unroll
            for (int tn = 0; tn < 4; ++tn)
                O[ob + tn * 16 + l16] = f2bf(Oacc[tm][tn][r] * linv[tm][r]);
        }
    }
}

// ---------------------------------------------------------------------------
extern "C" void kernel_launch(void* const* d_in, const int* in_sizes, int n_in,
                              void* d_out, int out_size, void* d_ws, size_t ws_size,
                              hipStream_t stream) {
    const float* x      = (const float*)d_in[0];
    const float* qkv_w  = (const float*)d_in[1];
    const float* qkv_b  = (const float*)d_in[2];
    const float* proj_w = (const float*)d_in[3];
    const float* proj_b = (const float*)d_in[4];
    float* out = (float*)d_out;

    unsigned short* q     = (unsigned short*)d_ws;
    unsigned short* k     = q + QKV_ELEMS;
    unsigned short* v     = k + QKV_ELEMS;
    unsigned short* slot4 = v + QKV_ELEMS;          // x_bf, then attn-out
    unsigned short* wq    = slot4 + QKV_ELEMS;
    unsigned short* wp    = wq + 2304 * 768;

    const int nx4 = 16384 * 768 / 4, nq4 = 2304 * 768 / 4, np4 = 768 * 768 / 4;
    f2bf3_kernel<<<(nx4 + nq4 + np4 + 255) / 256, 256, 0, stream>>>(
        x, slot4, nx4, qkv_w, wq, nq4, proj_w, wp, np4);

    qkv_gemm_mfma<<<dim3(18, 128), 256, 0, stream>>>(
        (const short*)slot4, (const short*)wq, qkv_b,
        (bf16*)q, (bf16*)k, (bf16*)v);

    attn_mfma<<<dim3(32 * 12 * 4), 256, 0, stream>>>(
        (const short*)q, (const short*)k, (const short*)v, (bf16*)slot4);

    proj_gemm_mfma<<<dim3(6, 128), 256, 0, stream>>>(
        (const short*)slot4, (const short*)wp, proj_b, out);
}